// Round 3
// baseline (420.244 us; speedup 1.0000x reference)
//
#include <hip/hip_runtime.h>
#include <math.h>

#define NN 50000
#define NE 400000
#define NREL 3
#define NCH 196   // ceil(NN/256) chunks per relation for the scan
// D = 128, H = 8, Dh = 16

typedef __bf16 bf16x8 __attribute__((ext_vector_type(8)));
typedef float floatx4 __attribute__((ext_vector_type(4)));

// ---- bf16 helpers (raw ushort; RNE encode, shift decode) --------------------
__device__ __forceinline__ unsigned short f2bf(float f) {
  unsigned int u = __float_as_uint(f);
  return (unsigned short)((u + 0x7fffu + ((u >> 16) & 1u)) >> 16);
}

// ---------------- weight prep: Wt[mat][n][k] bf16 (n = output col) -----------
// mats 0-2: layer1 rel 0-2; 3-5: layer2; 6: Wc1. Rows 128-143 (mats 0-5):
// wal/war columns appended so the MFMA's 9th n-tile produces el/er directly.
__global__ __launch_bounds__(256) void prep_wt(
    const float* __restrict__ W1, const float* __restrict__ W2,
    const float* __restrict__ Wc1, unsigned short* __restrict__ Wt) {
  int mat = blockIdx.x >> 3, slab = blockIdx.x & 7;
  const float* Wsrc = mat < 3 ? W1 + mat * 16384
                    : (mat < 6 ? W2 + (mat - 3) * 16384 : Wc1);
  unsigned short* dst = Wt + (size_t)mat * 144 * 128;
  int k0 = slab * 16;
#pragma unroll
  for (int i = 0; i < 8; ++i) {
    int idx = i * 256 + threadIdx.x;      // 0..2047
    int k = k0 + (idx >> 7), nn = idx & 127;
    dst[nn * 128 + k] = f2bf(Wsrc[k * 128 + nn]);
  }
}

// wal[k][h] = sum_d W[k][h*16+d]*al[h*16+d]  -> Wt rows 128+h (el) / 136+h (er)
__global__ __launch_bounds__(256) void prep_attn(
    const float* __restrict__ W1, const float* __restrict__ W2,
    const float* __restrict__ al1, const float* __restrict__ ar1,
    const float* __restrict__ al2, const float* __restrict__ ar2,
    unsigned short* __restrict__ Wt) {
  int mat = blockIdx.x;   // 0..5
  const float* Wsrc = mat < 3 ? W1 + mat * 16384 : W2 + (mat - 3) * 16384;
  const float* alp = mat < 3 ? al1 + mat * 128 : al2 + (mat - 3) * 128;
  const float* arp = mat < 3 ? ar1 + mat * 128 : ar2 + (mat - 3) * 128;
  unsigned short* dst = Wt + (size_t)mat * 144 * 128;
#pragma unroll
  for (int i = 0; i < 8; ++i) {
    int j = i * 256 + threadIdx.x;        // 0..2047
    int half = j >> 10, jj = j & 1023;
    int k = jj >> 3, h = jj & 7;
    const float* av = half ? arp : alp;
    float s = 0.f;
#pragma unroll
    for (int d = 0; d < 16; ++d) s += Wsrc[k * 128 + h * 16 + d] * av[h * 16 + d];
    dst[(128 + half * 8 + h) * 128 + k] = f2bf(s);
  }
}

// ---------------- fused 3-relation MFMA GEMM + attn coefficients -------------
// Block: 256 thr (4 waves), 64 rows. Xs staged once (f32->bf16); per relation
// Ws re-staged, K-loop of 4x(1 A-frag + 9 B-frag + 9 MFMA), 9th tile = el/er.
__global__ __launch_bounds__(256) void gemm3_attn_mfma(
    const float* __restrict__ X, const unsigned short* __restrict__ Wt,
    unsigned short* __restrict__ hp, float* __restrict__ el,
    float* __restrict__ er, int n) {
  __shared__ unsigned short Xs[64 * 136];   // pad 8: 2-way-bank-free
  __shared__ unsigned short Ws[144 * 136];
  int t = threadIdx.x;
  int rowbase = blockIdx.x * 64;

  // stage X -> bf16 LDS
  const float4* X4 = (const float4*)X;
#pragma unroll
  for (int i = 0; i < 8; ++i) {
    int v = t + i * 256;                  // 0..2047
    int row = v >> 5, k4 = (v & 31) * 4;
    float4 x = make_float4(0.f, 0.f, 0.f, 0.f);
    if (rowbase + row < n) x = X4[(size_t)(rowbase + row) * 32 + (v & 31)];
    ushort4 p;
    p.x = f2bf(x.x); p.y = f2bf(x.y); p.z = f2bf(x.z); p.w = f2bf(x.w);
    *(ushort4*)&Xs[row * 136 + k4] = p;
  }

  int lane = t & 63, wave = t >> 6;
  int quad = lane >> 4, l = lane & 15;

  for (int r = 0; r < NREL; ++r) {
    __syncthreads();                      // Xs ready / prior readers done
    const uint4* WtR = (const uint4*)(Wt + (size_t)r * 144 * 128);
#pragma unroll
    for (int i = 0; i < 9; ++i) {
      int v = t + i * 256;                // 0..2303
      ((uint4*)Ws)[(v >> 4) * 17 + (v & 15)] = WtR[v];
    }
    __syncthreads();

    floatx4 acc[9];
#pragma unroll
    for (int i = 0; i < 9; ++i) acc[i] = floatx4{0.f, 0.f, 0.f, 0.f};
#pragma unroll
    for (int ks = 0; ks < 4; ++ks) {
      bf16x8 a = *(const bf16x8*)&Xs[(wave * 16 + l) * 136 + ks * 32 + quad * 8];
#pragma unroll
      for (int nt = 0; nt < 9; ++nt) {
        bf16x8 b = *(const bf16x8*)&Ws[(nt * 16 + l) * 136 + ks * 32 + quad * 8];
        acc[nt] = __builtin_amdgcn_mfma_f32_16x16x32_bf16(a, b, acc[nt], 0, 0, 0);
      }
    }

    unsigned short* hpR = hp + (size_t)r * NN * 128;
    float* elR = el + (size_t)r * NN * 8;
    float* erR = er + (size_t)r * NN * 8;
    int r0 = rowbase + wave * 16 + quad * 4;
#pragma unroll
    for (int reg = 0; reg < 4; ++reg) {
      int row = r0 + reg;
      if (row < n) {
#pragma unroll
        for (int nt = 0; nt < 8; ++nt)
          hpR[(size_t)row * 128 + nt * 16 + l] = f2bf(acc[nt][reg]);
        if (l < 8) elR[row * 8 + l] = acc[8][reg];
        else       erR[row * 8 + (l - 8)] = acc[8][reg];
      }
    }
  }
}

// ---------------- head GEMM + fused classifier -------------------------------
// out[row] = relu(X@Wc1 + bc1) . Wc2 + bc2
__global__ __launch_bounds__(256) void gemm_head_mfma(
    const float* __restrict__ X, const unsigned short* __restrict__ Wt,
    const float* __restrict__ bc1, const float* __restrict__ wc2,
    const float* __restrict__ bc2, float* __restrict__ out, int n) {
  __shared__ unsigned short Xs[64 * 136];
  __shared__ unsigned short Ws[128 * 136];
  int t = threadIdx.x;
  int rowbase = blockIdx.x * 64;

  const float4* X4 = (const float4*)X;
#pragma unroll
  for (int i = 0; i < 8; ++i) {
    int v = t + i * 256;
    int row = v >> 5, k4 = (v & 31) * 4;
    float4 x = make_float4(0.f, 0.f, 0.f, 0.f);
    if (rowbase + row < n) x = X4[(size_t)(rowbase + row) * 32 + (v & 31)];
    ushort4 p;
    p.x = f2bf(x.x); p.y = f2bf(x.y); p.z = f2bf(x.z); p.w = f2bf(x.w);
    *(ushort4*)&Xs[row * 136 + k4] = p;
  }
  const uint4* WtR = (const uint4*)Wt;
#pragma unroll
  for (int i = 0; i < 8; ++i) {
    int v = t + i * 256;                  // 0..2047
    ((uint4*)Ws)[(v >> 4) * 17 + (v & 15)] = WtR[v];
  }
  __syncthreads();

  int lane = t & 63, wave = t >> 6;
  int quad = lane >> 4, l = lane & 15;

  floatx4 acc[8];
#pragma unroll
  for (int i = 0; i < 8; ++i) acc[i] = floatx4{0.f, 0.f, 0.f, 0.f};
#pragma unroll
  for (int ks = 0; ks < 4; ++ks) {
    bf16x8 a = *(const bf16x8*)&Xs[(wave * 16 + l) * 136 + ks * 32 + quad * 8];
#pragma unroll
    for (int nt = 0; nt < 8; ++nt) {
      bf16x8 b = *(const bf16x8*)&Ws[(nt * 16 + l) * 136 + ks * 32 + quad * 8];
      acc[nt] = __builtin_amdgcn_mfma_f32_16x16x32_bf16(a, b, acc[nt], 0, 0, 0);
    }
  }

  float bv[8], wv[8];
#pragma unroll
  for (int nt = 0; nt < 8; ++nt) {
    bv[nt] = bc1[nt * 16 + l];
    wv[nt] = wc2[nt * 16 + l];
  }
  int r0 = rowbase + wave * 16 + quad * 4;
#pragma unroll
  for (int reg = 0; reg < 4; ++reg) {
    float s = 0.f;
#pragma unroll
    for (int nt = 0; nt < 8; ++nt)
      s += fmaxf(acc[nt][reg] + bv[nt], 0.f) * wv[nt];
    s += __shfl_xor(s, 1); s += __shfl_xor(s, 2);
    s += __shfl_xor(s, 4); s += __shfl_xor(s, 8);
    int row = r0 + reg;
    if (l == 0 && row < n) out[row] = s + bc2[0];
  }
}

// ---------------- CSR build (rank trick: no atomic in scatter) ---------------
__global__ __launch_bounds__(256) void hist_kernel(
    const int* __restrict__ edst, int* __restrict__ cnt, int* __restrict__ rank) {
  int t = blockIdx.x * 256 + threadIdx.x;
  if (t >= NREL * NE) return;
  int r = t / NE;
  rank[t] = atomicAdd(&cnt[r * NN + edst[t]], 1);
}

__global__ __launch_bounds__(256) void scan1(
    const int* __restrict__ cnt, int* __restrict__ partials) {
  __shared__ int s[256];
  int r = blockIdx.x / NCH, c = blockIdx.x % NCH;
  int i = c * 256 + threadIdx.x;
  s[threadIdx.x] = (i < NN) ? cnt[r * NN + i] : 0;
  __syncthreads();
  for (int off = 128; off; off >>= 1) {
    if (threadIdx.x < off) s[threadIdx.x] += s[threadIdx.x + off];
    __syncthreads();
  }
  if (threadIdx.x == 0) partials[r * NCH + c] = s[0];
}

__global__ __launch_bounds__(256) void scan2(int* __restrict__ partials) {
  __shared__ int s[256];
  int r = blockIdx.x;
  int t = threadIdx.x;
  int v = (t < NCH) ? partials[r * NCH + t] : 0;
  s[t] = v;
  __syncthreads();
  for (int off = 1; off < 256; off <<= 1) {
    int x = (t >= off) ? s[t - off] : 0;
    __syncthreads();
    s[t] += x;
    __syncthreads();
  }
  if (t < NCH) partials[r * NCH + t] = s[t] - v;  // exclusive
}

__global__ __launch_bounds__(256) void scan3(
    const int* __restrict__ cnt, const int* __restrict__ partials,
    int* __restrict__ rowptr) {
  __shared__ int s[256];
  int r = blockIdx.x / NCH, c = blockIdx.x % NCH;
  int t = threadIdx.x;
  int i = c * 256 + t;
  int v = (i < NN) ? cnt[r * NN + i] : 0;
  s[t] = v;
  __syncthreads();
  for (int off = 1; off < 256; off <<= 1) {
    int x = (t >= off) ? s[t - off] : 0;
    __syncthreads();
    s[t] += x;
    __syncthreads();
  }
  int base = partials[r * NCH + c];
  if (i < NN) rowptr[r * (NN + 1) + i] = base + s[t] - v;
  if (c == NCH - 1 && t == 0) rowptr[r * (NN + 1) + NN] = NE;
}

__global__ __launch_bounds__(256) void scatter_kernel(
    const int* __restrict__ esrc, const int* __restrict__ edst,
    const int* __restrict__ rowptr, const int* __restrict__ rank,
    int* __restrict__ col) {
  int t = blockIdx.x * 256 + threadIdx.x;
  if (t >= NREL * NE) return;
  int r = t / NE;
  int pos = rowptr[r * (NN + 1) + edst[t]] + rank[t];
  col[(size_t)r * NE + pos] = esrc[t];
}

// ---------------- fused 3-relation gather + layer tail -----------------------
// Joint chunk loop over all 3 relations; per iteration the phases are ordered
// A0..A2 (alpha/exp + next-col prefetch) -> B0..B2 (24 hp-row loads in flight)
// -> next-el prefetch -> sched_barrier -> C0..C2 (swizzle+FMA). First-chunk
// col+el prefetched pre-loop, so a wave exposes ~2 L3 round trips, not ~6.
__global__ __launch_bounds__(256) void gather_all(
    const int* __restrict__ rowptr, const int* __restrict__ col,
    const float* __restrict__ el, const float* __restrict__ er,
    const unsigned short* __restrict__ hp, const float* __restrict__ b,
    float* __restrict__ h1, const float* __restrict__ g,
    const float* __restrict__ beta, int mode) {
  int wid = (blockIdx.x * 256 + threadIdx.x) >> 6;
  int lane = threadIdx.x & 63;
  if (wid >= NN) return;
  int h = lane >> 3;    // alpha-phase head; equals channel-head (c>>4)
  int eoff = lane & 7;  // alpha-phase edge slot within chunk
  int c = lane * 2;     // channel pair owned in accumulation
  int lane4 = lane * 4;

  // hoisted: rowptr, er (all rels), bias, LN params, residual
  int st0, st1, st2, ee0, ee1, ee2;
  {
    const int* rp = rowptr;
    st0 = rp[wid]; ee0 = rp[wid + 1];
    rp += NN + 1;
    st1 = rp[wid]; ee1 = rp[wid + 1];
    rp += NN + 1;
    st2 = rp[wid]; ee2 = rp[wid + 1];
  }
  float erv0 = er[wid * 8 + h];
  float erv1 = er[(size_t)NN * 8 + wid * 8 + h];
  float erv2 = er[(size_t)2 * NN * 8 + wid * 8 + h];
  float b0x = b[c], b1x = b[128 + c], b2x = b[256 + c];
  float b0y = b[c + 1], b1y = b[128 + c + 1], b2y = b[256 + c + 1];
  float2* hptr = (float2*)&h1[(size_t)wid * 128 + c];
  float2 r1 = make_float2(0.f, 0.f);
  float gx = 0.f, gy = 0.f, btx = 0.f, bty = 0.f;
  if (mode) {
    r1 = *hptr;
    gx = g[c]; gy = g[c + 1];
    btx = beta[c]; bty = beta[c + 1];
  }

  const int* clp0 = col;
  const int* clp1 = col + NE;
  const int* clp2 = col + 2 * NE;
  const float* elp0 = el;
  const float* elp1 = el + (size_t)NN * 8;
  const float* elp2 = el + (size_t)2 * NN * 8;
  const char* hpb0 = (const char*)hp;
  const char* hpb1 = hpb0 + (size_t)NN * 256;
  const char* hpb2 = hpb1 + (size_t)NN * 256;

  // clamped last index per rel (valid even for empty rows at array end)
  int la0 = ee0 - 1; if (la0 < st0) la0 = st0; if (la0 >= NE) la0 = NE - 1;
  int la1 = ee1 - 1; if (la1 < st1) la1 = st1; if (la1 >= NE) la1 = NE - 1;
  int la2 = ee2 - 1; if (la2 < st2) la2 = st2; if (la2 >= NE) la2 = NE - 1;

  // first-chunk col + el prefetch (all rels concurrently)
  int i0 = st0 + eoff, i1 = st1 + eoff, i2 = st2 + eoff;
  int cv0 = clp0[i0 < la0 ? i0 : la0];
  int cv1 = clp1[i1 < la1 ? i1 : la1];
  int cv2 = clp2[i2 < la2 ? i2 : la2];
  float ev0 = elp0[cv0 * 8 + h];
  float ev1 = elp1[cv1 * 8 + h];
  float ev2 = elp2[cv2 * 8 + h];

  int bb0 = st0, bb1 = st1, bb2 = st2;
  float den0 = 0.f, den1 = 0.f, den2 = 0.f;
  float sx0 = 0.f, sy0 = 0.f, sx1 = 0.f, sy1 = 0.f, sx2 = 0.f, sy2 = 0.f;

#define A_PHASE(R)                                                             \
  if (a##R) {                                                                  \
    int ni_ = bb##R + 8 + eoff;                                                \
    cm##R = clp##R[ni_ < la##R ? ni_ : la##R];                                 \
    float e_ = ev##R + erv##R;                                                 \
    e_ = fmaxf(e_, 0.2f * e_);                                                 \
    float x_ = (bb##R + eoff < ee##R) ? __expf(e_) : 0.f;                      \
    den##R += x_;                                                              \
    xi##R = __float_as_uint(x_);                                               \
  }

#define LOAD_EDGE(R, JJ)                                                       \
  {                                                                            \
    int s_ = __builtin_amdgcn_readlane(cv##R, JJ);                             \
    u##R##_##JJ = *(const unsigned int*)(hpb##R + (size_t)s_ * 256 + lane4);   \
  }

#define B_PHASE(R)                                                             \
  if (a##R) {                                                                  \
    LOAD_EDGE(R, 0) LOAD_EDGE(R, 1) LOAD_EDGE(R, 2) LOAD_EDGE(R, 3)            \
    LOAD_EDGE(R, 4) LOAD_EDGE(R, 5) LOAD_EDGE(R, 6) LOAD_EDGE(R, 7)            \
  }

#define FMA_EDGE(R, JJ, PAT)                                                   \
  {                                                                            \
    float xe_ = __uint_as_float(__builtin_amdgcn_ds_swizzle(xi##R, PAT));      \
    sx##R += xe_ * __uint_as_float(u##R##_##JJ << 16);                         \
    sy##R += xe_ * __uint_as_float(u##R##_##JJ & 0xffff0000u);                 \
  }

#define C_PHASE(R)                                                             \
  if (a##R) {                                                                  \
    FMA_EDGE(R, 0, 0x18) FMA_EDGE(R, 1, 0x38) FMA_EDGE(R, 2, 0x58)             \
    FMA_EDGE(R, 3, 0x78) FMA_EDGE(R, 4, 0x98) FMA_EDGE(R, 5, 0xb8)             \
    FMA_EDGE(R, 6, 0xd8) FMA_EDGE(R, 7, 0xf8)                                  \
  }

  for (;;) {
    bool a0 = bb0 < ee0, a1 = bb1 < ee1, a2 = bb2 < ee2;
    if (!(a0 | a1 | a2)) break;
    int cm0 = cv0, cm1 = cv1, cm2 = cv2;
    unsigned int xi0 = 0, xi1 = 0, xi2 = 0;
    unsigned int u0_0, u0_1, u0_2, u0_3, u0_4, u0_5, u0_6, u0_7;
    unsigned int u1_0, u1_1, u1_2, u1_3, u1_4, u1_5, u1_6, u1_7;
    unsigned int u2_0, u2_1, u2_2, u2_3, u2_4, u2_5, u2_6, u2_7;
    A_PHASE(0) A_PHASE(1) A_PHASE(2)
    B_PHASE(0) B_PHASE(1) B_PHASE(2)
    float evn0 = ev0, evn1 = ev1, evn2 = ev2;
    if (a0) evn0 = elp0[cm0 * 8 + h];
    if (a1) evn1 = elp1[cm1 * 8 + h];
    if (a2) evn2 = elp2[cm2 * 8 + h];
    __builtin_amdgcn_sched_barrier(0);
    C_PHASE(0) C_PHASE(1) C_PHASE(2)
    bb0 += 8; bb1 += 8; bb2 += 8;
    cv0 = cm0; cv1 = cm1; cv2 = cm2;
    ev0 = evn0; ev1 = evn1; ev2 = evn2;
  }

#undef A_PHASE
#undef LOAD_EDGE
#undef B_PHASE
#undef FMA_EDGE
#undef C_PHASE

  float ax = 0.f, ay = 0.f;
  if (ee0 > st0) {
    float d = den0;
    d += __shfl_xor(d, 1); d += __shfl_xor(d, 2); d += __shfl_xor(d, 4);
    float inv = 1.f / d;
    ax += sx0 * inv; ay += sy0 * inv;
  }
  if (ee1 > st1) {
    float d = den1;
    d += __shfl_xor(d, 1); d += __shfl_xor(d, 2); d += __shfl_xor(d, 4);
    float inv = 1.f / d;
    ax += sx1 * inv; ay += sy1 * inv;
  }
  if (ee2 > st2) {
    float d = den2;
    d += __shfl_xor(d, 1); d += __shfl_xor(d, 2); d += __shfl_xor(d, 4);
    float inv = 1.f / d;
    ax += sx2 * inv; ay += sy2 * inv;
  }

  float bx = b0x + b1x + b2x;
  float by = b0y + b1y + b2y;
  if (mode == 0) {
    *hptr = make_float2(fmaxf(ax + bx, 0.f), fmaxf(ay + by, 0.f));
  } else {
    float vx = ax + bx + r1.x;
    float vy = ay + by + r1.y;
    float s = vx + vy;
#pragma unroll
    for (int off = 32; off; off >>= 1) s += __shfl_xor(s, off);
    float mu = s * (1.f / 128.f);
    float dx = vx - mu, dy = vy - mu;
    float sq = dx * dx + dy * dy;
#pragma unroll
    for (int off = 32; off; off >>= 1) sq += __shfl_xor(sq, off);
    float rstd = rsqrtf(sq * (1.f / 128.f) + 1e-5f);
    *hptr = make_float2(dx * rstd * gx + btx, dy * rstd * gy + bty);
  }
}

extern "C" void kernel_launch(void* const* d_in, const int* in_sizes, int n_in,
                              void* d_out, int out_size, void* d_ws, size_t ws_size,
                              hipStream_t stream) {
  const float* feat = (const float*)d_in[0];
  const int* esrc = (const int*)d_in[1];
  const int* edst = (const int*)d_in[2];
  const float* W1 = (const float*)d_in[3];
  const float* al1 = (const float*)d_in[4];
  const float* ar1 = (const float*)d_in[5];
  const float* b1 = (const float*)d_in[6];
  const float* W2 = (const float*)d_in[7];
  const float* al2 = (const float*)d_in[8];
  const float* ar2 = (const float*)d_in[9];
  const float* b2 = (const float*)d_in[10];
  const float* lng = (const float*)d_in[11];
  const float* lnb = (const float*)d_in[12];
  const float* Wc1 = (const float*)d_in[13];
  const float* bc1 = (const float*)d_in[14];
  const float* Wc2 = (const float*)d_in[15];
  const float* bc2 = (const float*)d_in[16];
  float* out = (float*)d_out;

  // workspace layout
  unsigned short* hp = (unsigned short*)d_ws;            // 3*NN*128 bf16
  float* el = (float*)(hp + (size_t)3 * NN * 128);       // 3*NN*8 f32
  float* er = el + (size_t)3 * NN * 8;                   // 3*NN*8 f32
  float* h1 = er + (size_t)3 * NN * 8;                   // NN*128 f32
  int* rowptr = (int*)(h1 + (size_t)NN * 128);           // 3*(NN+1)
  int* col = rowptr + NREL * (NN + 1);                   // 3*NE
  int* cnt = col + (size_t)NREL * NE;                    // 3*NN
  int* partials = cnt + NREL * NN;                       // 3*NCH
  unsigned short* Wt = (unsigned short*)(((uintptr_t)(partials + NREL * NCH) + 15)
                                         & ~(uintptr_t)15);  // 7*144*128 bf16
  int* rank = (int*)el;  // alias: rank (3*NE) dead before first el write

  const int gemm_grid = (NN + 63) / 64;          // 782
  const int edge_grid = (NREL * NE + 255) / 256; // 4688
  const int gg_grid = (NN * 64) / 256;           // 12500 (wave per dst)

  // --- weight prep (bf16 transpose + fused wal/war columns) ---
  prep_wt<<<56, 256, 0, stream>>>(W1, W2, Wc1, Wt);
  prep_attn<<<6, 256, 0, stream>>>(W1, W2, al1, ar1, al2, ar2, Wt);

  // --- CSR build (edges shared by both layers) ---
  (void)hipMemsetAsync(cnt, 0, (size_t)NREL * NN * sizeof(int), stream);
  hist_kernel<<<edge_grid, 256, 0, stream>>>(edst, cnt, rank);
  scan1<<<NREL * NCH, 256, 0, stream>>>(cnt, partials);
  scan2<<<NREL, 256, 0, stream>>>(partials);
  scan3<<<NREL * NCH, 256, 0, stream>>>(cnt, partials, rowptr);
  scatter_kernel<<<edge_grid, 256, 0, stream>>>(esrc, edst, rowptr, rank, col);

  // --- layer 1 ---
  gemm3_attn_mfma<<<gemm_grid, 256, 0, stream>>>(feat, Wt, hp, el, er, NN);
  gather_all<<<gg_grid, 256, 0, stream>>>(rowptr, col, el, er, hp, b1,
                                          h1, nullptr, nullptr, 0);
  // --- layer 2 ---
  gemm3_attn_mfma<<<gemm_grid, 256, 0, stream>>>(
      h1, Wt + (size_t)3 * 144 * 128, hp, el, er, NN);
  gather_all<<<gg_grid, 256, 0, stream>>>(rowptr, col, el, er, hp, b2,
                                          h1, lng, lnb, 1);
  // --- classifier head ---
  gemm_head_mfma<<<gemm_grid, 256, 0, stream>>>(
      h1, Wt + (size_t)6 * 144 * 128, bc1, Wc2, bc2, out, NN);
}

// Round 4
// 383.792 us; speedup vs baseline: 1.0950x; 1.0950x over previous
//
#include <hip/hip_runtime.h>
#include <math.h>

#define NN 50000
#define NE 400000
#define NREL 3
#define NCH 196   // ceil(NN/256) chunks per relation for the scan
// D = 128, H = 8, Dh = 16

typedef __bf16 bf16x8 __attribute__((ext_vector_type(8)));
typedef float floatx4 __attribute__((ext_vector_type(4)));

// ---- bf16 helpers (raw ushort; RNE encode, shift decode) --------------------
__device__ __forceinline__ unsigned short f2bf(float f) {
  unsigned int u = __float_as_uint(f);
  return (unsigned short)((u + 0x7fffu + ((u >> 16) & 1u)) >> 16);
}

// ---------------- weight prep: Wt[mat][n][k] bf16 (n = output col) -----------
// mats 0-2: layer1 rel 0-2; 3-5: layer2; 6: Wc1. Rows 128-143 (mats 0-5):
// wal/war columns appended so the MFMA's 9th n-tile produces el/er directly.
__global__ __launch_bounds__(256) void prep_wt(
    const float* __restrict__ W1, const float* __restrict__ W2,
    const float* __restrict__ Wc1, unsigned short* __restrict__ Wt) {
  int mat = blockIdx.x >> 3, slab = blockIdx.x & 7;
  const float* Wsrc = mat < 3 ? W1 + mat * 16384
                    : (mat < 6 ? W2 + (mat - 3) * 16384 : Wc1);
  unsigned short* dst = Wt + (size_t)mat * 144 * 128;
  int k0 = slab * 16;
#pragma unroll
  for (int i = 0; i < 8; ++i) {
    int idx = i * 256 + threadIdx.x;      // 0..2047
    int k = k0 + (idx >> 7), nn = idx & 127;
    dst[nn * 128 + k] = f2bf(Wsrc[k * 128 + nn]);
  }
}

// wal[k][h] = sum_d W[k][h*16+d]*al[h*16+d]  -> Wt rows 128+h (el) / 136+h (er)
__global__ __launch_bounds__(256) void prep_attn(
    const float* __restrict__ W1, const float* __restrict__ W2,
    const float* __restrict__ al1, const float* __restrict__ ar1,
    const float* __restrict__ al2, const float* __restrict__ ar2,
    unsigned short* __restrict__ Wt) {
  int mat = blockIdx.x;   // 0..5
  const float* Wsrc = mat < 3 ? W1 + mat * 16384 : W2 + (mat - 3) * 16384;
  const float* alp = mat < 3 ? al1 + mat * 128 : al2 + (mat - 3) * 128;
  const float* arp = mat < 3 ? ar1 + mat * 128 : ar2 + (mat - 3) * 128;
  unsigned short* dst = Wt + (size_t)mat * 144 * 128;
#pragma unroll
  for (int i = 0; i < 8; ++i) {
    int j = i * 256 + threadIdx.x;        // 0..2047
    int half = j >> 10, jj = j & 1023;
    int k = jj >> 3, h = jj & 7;
    const float* av = half ? arp : alp;
    float s = 0.f;
#pragma unroll
    for (int d = 0; d < 16; ++d) s += Wsrc[k * 128 + h * 16 + d] * av[h * 16 + d];
    dst[(128 + half * 8 + h) * 128 + k] = f2bf(s);
  }
}

// ---------------- fused 3-relation MFMA GEMM + attn coefficients -------------
// Block: 256 thr (4 waves), 64 rows. Xs staged once (f32->bf16); per relation
// Ws re-staged, K-loop of 4x(1 A-frag + 9 B-frag + 9 MFMA), 9th tile = el/er.
__global__ __launch_bounds__(256) void gemm3_attn_mfma(
    const float* __restrict__ X, const unsigned short* __restrict__ Wt,
    unsigned short* __restrict__ hp, float* __restrict__ el,
    float* __restrict__ er, int n) {
  __shared__ unsigned short Xs[64 * 136];   // pad 8: 2-way-bank-free
  __shared__ unsigned short Ws[144 * 136];
  int t = threadIdx.x;
  int rowbase = blockIdx.x * 64;

  // stage X -> bf16 LDS
  const float4* X4 = (const float4*)X;
#pragma unroll
  for (int i = 0; i < 8; ++i) {
    int v = t + i * 256;                  // 0..2047
    int row = v >> 5, k4 = (v & 31) * 4;
    float4 x = make_float4(0.f, 0.f, 0.f, 0.f);
    if (rowbase + row < n) x = X4[(size_t)(rowbase + row) * 32 + (v & 31)];
    ushort4 p;
    p.x = f2bf(x.x); p.y = f2bf(x.y); p.z = f2bf(x.z); p.w = f2bf(x.w);
    *(ushort4*)&Xs[row * 136 + k4] = p;
  }

  int lane = t & 63, wave = t >> 6;
  int quad = lane >> 4, l = lane & 15;

  for (int r = 0; r < NREL; ++r) {
    __syncthreads();                      // Xs ready / prior readers done
    const uint4* WtR = (const uint4*)(Wt + (size_t)r * 144 * 128);
#pragma unroll
    for (int i = 0; i < 9; ++i) {
      int v = t + i * 256;                // 0..2303
      ((uint4*)Ws)[(v >> 4) * 17 + (v & 15)] = WtR[v];
    }
    __syncthreads();

    floatx4 acc[9];
#pragma unroll
    for (int i = 0; i < 9; ++i) acc[i] = floatx4{0.f, 0.f, 0.f, 0.f};
#pragma unroll
    for (int ks = 0; ks < 4; ++ks) {
      bf16x8 a = *(const bf16x8*)&Xs[(wave * 16 + l) * 136 + ks * 32 + quad * 8];
#pragma unroll
      for (int nt = 0; nt < 9; ++nt) {
        bf16x8 b = *(const bf16x8*)&Ws[(nt * 16 + l) * 136 + ks * 32 + quad * 8];
        acc[nt] = __builtin_amdgcn_mfma_f32_16x16x32_bf16(a, b, acc[nt], 0, 0, 0);
      }
    }

    unsigned short* hpR = hp + (size_t)r * NN * 128;
    float* elR = el + (size_t)r * NN * 8;
    float* erR = er + (size_t)r * NN * 8;
    int r0 = rowbase + wave * 16 + quad * 4;
#pragma unroll
    for (int reg = 0; reg < 4; ++reg) {
      int row = r0 + reg;
      if (row < n) {
#pragma unroll
        for (int nt = 0; nt < 8; ++nt)
          hpR[(size_t)row * 128 + nt * 16 + l] = f2bf(acc[nt][reg]);
        if (l < 8) elR[row * 8 + l] = acc[8][reg];
        else       erR[row * 8 + (l - 8)] = acc[8][reg];
      }
    }
  }
}

// ---------------- head GEMM + fused classifier -------------------------------
// out[row] = relu(X@Wc1 + bc1) . Wc2 + bc2
__global__ __launch_bounds__(256) void gemm_head_mfma(
    const float* __restrict__ X, const unsigned short* __restrict__ Wt,
    const float* __restrict__ bc1, const float* __restrict__ wc2,
    const float* __restrict__ bc2, float* __restrict__ out, int n) {
  __shared__ unsigned short Xs[64 * 136];
  __shared__ unsigned short Ws[128 * 136];
  int t = threadIdx.x;
  int rowbase = blockIdx.x * 64;

  const float4* X4 = (const float4*)X;
#pragma unroll
  for (int i = 0; i < 8; ++i) {
    int v = t + i * 256;
    int row = v >> 5, k4 = (v & 31) * 4;
    float4 x = make_float4(0.f, 0.f, 0.f, 0.f);
    if (rowbase + row < n) x = X4[(size_t)(rowbase + row) * 32 + (v & 31)];
    ushort4 p;
    p.x = f2bf(x.x); p.y = f2bf(x.y); p.z = f2bf(x.z); p.w = f2bf(x.w);
    *(ushort4*)&Xs[row * 136 + k4] = p;
  }
  const uint4* WtR = (const uint4*)Wt;
#pragma unroll
  for (int i = 0; i < 8; ++i) {
    int v = t + i * 256;                  // 0..2047
    ((uint4*)Ws)[(v >> 4) * 17 + (v & 15)] = WtR[v];
  }
  __syncthreads();

  int lane = t & 63, wave = t >> 6;
  int quad = lane >> 4, l = lane & 15;

  floatx4 acc[8];
#pragma unroll
  for (int i = 0; i < 8; ++i) acc[i] = floatx4{0.f, 0.f, 0.f, 0.f};
#pragma unroll
  for (int ks = 0; ks < 4; ++ks) {
    bf16x8 a = *(const bf16x8*)&Xs[(wave * 16 + l) * 136 + ks * 32 + quad * 8];
#pragma unroll
    for (int nt = 0; nt < 8; ++nt) {
      bf16x8 b = *(const bf16x8*)&Ws[(nt * 16 + l) * 136 + ks * 32 + quad * 8];
      acc[nt] = __builtin_amdgcn_mfma_f32_16x16x32_bf16(a, b, acc[nt], 0, 0, 0);
    }
  }

  float bv[8], wv[8];
#pragma unroll
  for (int nt = 0; nt < 8; ++nt) {
    bv[nt] = bc1[nt * 16 + l];
    wv[nt] = wc2[nt * 16 + l];
  }
  int r0 = rowbase + wave * 16 + quad * 4;
#pragma unroll
  for (int reg = 0; reg < 4; ++reg) {
    float s = 0.f;
#pragma unroll
    for (int nt = 0; nt < 8; ++nt)
      s += fmaxf(acc[nt][reg] + bv[nt], 0.f) * wv[nt];
    s += __shfl_xor(s, 1); s += __shfl_xor(s, 2);
    s += __shfl_xor(s, 4); s += __shfl_xor(s, 8);
    int row = r0 + reg;
    if (l == 0 && row < n) out[row] = s + bc2[0];
  }
}

// ---------------- CSR build (rank trick: no atomic in scatter) ---------------
__global__ __launch_bounds__(256) void hist_kernel(
    const int* __restrict__ edst, int* __restrict__ cnt, int* __restrict__ rank) {
  int t = blockIdx.x * 256 + threadIdx.x;
  if (t >= NREL * NE) return;
  int r = t / NE;
  rank[t] = atomicAdd(&cnt[r * NN + edst[t]], 1);
}

__global__ __launch_bounds__(256) void scan1(
    const int* __restrict__ cnt, int* __restrict__ partials) {
  __shared__ int s[256];
  int r = blockIdx.x / NCH, c = blockIdx.x % NCH;
  int i = c * 256 + threadIdx.x;
  s[threadIdx.x] = (i < NN) ? cnt[r * NN + i] : 0;
  __syncthreads();
  for (int off = 128; off; off >>= 1) {
    if (threadIdx.x < off) s[threadIdx.x] += s[threadIdx.x + off];
    __syncthreads();
  }
  if (threadIdx.x == 0) partials[r * NCH + c] = s[0];
}

__global__ __launch_bounds__(256) void scan2(int* __restrict__ partials) {
  __shared__ int s[256];
  int r = blockIdx.x;
  int t = threadIdx.x;
  int v = (t < NCH) ? partials[r * NCH + t] : 0;
  s[t] = v;
  __syncthreads();
  for (int off = 1; off < 256; off <<= 1) {
    int x = (t >= off) ? s[t - off] : 0;
    __syncthreads();
    s[t] += x;
    __syncthreads();
  }
  if (t < NCH) partials[r * NCH + t] = s[t] - v;  // exclusive
}

__global__ __launch_bounds__(256) void scan3(
    const int* __restrict__ cnt, const int* __restrict__ partials,
    int* __restrict__ rowptr) {
  __shared__ int s[256];
  int r = blockIdx.x / NCH, c = blockIdx.x % NCH;
  int t = threadIdx.x;
  int i = c * 256 + t;
  int v = (i < NN) ? cnt[r * NN + i] : 0;
  s[t] = v;
  __syncthreads();
  for (int off = 1; off < 256; off <<= 1) {
    int x = (t >= off) ? s[t - off] : 0;
    __syncthreads();
    s[t] += x;
    __syncthreads();
  }
  int base = partials[r * NCH + c];
  if (i < NN) rowptr[r * (NN + 1) + i] = base + s[t] - v;
  if (c == NCH - 1 && t == 0) rowptr[r * (NN + 1) + NN] = NE;
}

__global__ __launch_bounds__(256) void scatter_kernel(
    const int* __restrict__ esrc, const int* __restrict__ edst,
    const int* __restrict__ rowptr, const int* __restrict__ rank,
    int* __restrict__ col) {
  int t = blockIdx.x * 256 + threadIdx.x;
  if (t >= NREL * NE) return;
  int r = t / NE;
  int pos = rowptr[r * (NN + 1) + edst[t]] + rank[t];
  col[(size_t)r * NE + pos] = esrc[t];
}

// ---------------- fused 3-relation gather + layer tail -----------------------
// Chunk-1 of ALL 3 relations is one straight-line block: col loads for chunk 1
// AND chunk 2 of all rels issued concurrently, then all 24 hp-row loads + 3 el
// loads back-to-back, then exp, then FMA phases with compiler-counted vmcnt.
// No sched_barrier; no dependent prefetch before compute (the R3 mistake).
// Tails (deg>8, ~45% of rel-rows) run the proven R2-style per-rel loop with
// their first col already in flight from the prologue.
__global__ __launch_bounds__(256) void gather_all(
    const int* __restrict__ rowptr, const int* __restrict__ col,
    const float* __restrict__ el, const float* __restrict__ er,
    const unsigned short* __restrict__ hp, const float* __restrict__ b,
    float* __restrict__ h1, const float* __restrict__ g,
    const float* __restrict__ beta, int mode) {
  int wid = (blockIdx.x * 256 + threadIdx.x) >> 6;
  int lane = threadIdx.x & 63;
  if (wid >= NN) return;
  int h = lane >> 3;    // alpha-phase head; equals channel-head (c>>4)
  int eoff = lane & 7;  // alpha-phase edge slot within chunk
  int c = lane * 2;     // channel pair owned in accumulation
  int lane4 = lane * 4;

  const int* rp0 = rowptr;
  const int* rp1 = rowptr + (NN + 1);
  const int* rp2 = rowptr + 2 * (NN + 1);
  int st0 = rp0[wid], ee0 = rp0[wid + 1];
  int st1 = rp1[wid], ee1 = rp1[wid + 1];
  int st2 = rp2[wid], ee2 = rp2[wid + 1];
  float erv0 = er[wid * 8 + h];
  float erv1 = er[(size_t)NN * 8 + wid * 8 + h];
  float erv2 = er[(size_t)2 * NN * 8 + wid * 8 + h];

  const int* clp0 = col;
  const int* clp1 = col + NE;
  const int* clp2 = col + 2 * NE;
  const float* elp0 = el;
  const float* elp1 = el + (size_t)NN * 8;
  const float* elp2 = el + (size_t)2 * NN * 8;
  const char* hpb0 = (const char*)hp;
  const char* hpb1 = hpb0 + (size_t)NN * 256;
  const char* hpb2 = hpb1 + (size_t)NN * 256;

  // clamped last index per rel (valid even for empty rows at array end)
  int la0 = ee0 - 1; if (la0 < st0) la0 = st0; if (la0 >= NE) la0 = NE - 1;
  int la1 = ee1 - 1; if (la1 < st1) la1 = st1; if (la1 >= NE) la1 = NE - 1;
  int la2 = ee2 - 1; if (la2 < st2) la2 = st2; if (la2 >= NE) la2 = NE - 1;

  // chunk-1 AND chunk-2 col loads, all rels, concurrently in flight
  int i0 = st0 + eoff, i1 = st1 + eoff, i2 = st2 + eoff;
  int j0 = i0 + 8, j1 = i1 + 8, j2 = i2 + 8;
  int cv0 = clp0[i0 < la0 ? i0 : la0];
  int cv1 = clp1[i1 < la1 ? i1 : la1];
  int cv2 = clp2[i2 < la2 ? i2 : la2];
  int cm0 = clp0[j0 < la0 ? j0 : la0];
  int cm1 = clp1[j1 < la1 ? j1 : la1];
  int cm2 = clp2[j2 < la2 ? j2 : la2];

  // chunk-1 el loads (parallel with the 24 hp loads below)
  float ev0 = elp0[cv0 * 8 + h];
  float ev1 = elp1[cv1 * 8 + h];
  float ev2 = elp2[cv2 * 8 + h];

  unsigned int u0_0, u0_1, u0_2, u0_3, u0_4, u0_5, u0_6, u0_7;
  unsigned int u1_0, u1_1, u1_2, u1_3, u1_4, u1_5, u1_6, u1_7;
  unsigned int u2_0, u2_1, u2_2, u2_3, u2_4, u2_5, u2_6, u2_7;

#define LOAD1(R, JJ)                                                           \
  {                                                                            \
    int s_ = __builtin_amdgcn_readlane(cv##R, JJ);                             \
    u##R##_##JJ = *(const unsigned int*)(hpb##R + (size_t)s_ * 256 + lane4);   \
  }
  LOAD1(0, 0) LOAD1(0, 1) LOAD1(0, 2) LOAD1(0, 3)
  LOAD1(0, 4) LOAD1(0, 5) LOAD1(0, 6) LOAD1(0, 7)
  LOAD1(1, 0) LOAD1(1, 1) LOAD1(1, 2) LOAD1(1, 3)
  LOAD1(1, 4) LOAD1(1, 5) LOAD1(1, 6) LOAD1(1, 7)
  LOAD1(2, 0) LOAD1(2, 1) LOAD1(2, 2) LOAD1(2, 3)
  LOAD1(2, 4) LOAD1(2, 5) LOAD1(2, 6) LOAD1(2, 7)
#undef LOAD1

  // exp (overlaps with hp loads in flight); x=0 masks invalid slots & empty rels
  float e0 = ev0 + erv0; e0 = fmaxf(e0, 0.2f * e0);
  float e1 = ev1 + erv1; e1 = fmaxf(e1, 0.2f * e1);
  float e2 = ev2 + erv2; e2 = fmaxf(e2, 0.2f * e2);
  float x0 = (i0 < ee0) ? __expf(e0) : 0.f;
  float x1 = (i1 < ee1) ? __expf(e1) : 0.f;
  float x2 = (i2 < ee2) ? __expf(e2) : 0.f;
  float den0 = x0, den1 = x1, den2 = x2;
  unsigned int xi0 = __float_as_uint(x0);
  unsigned int xi1 = __float_as_uint(x1);
  unsigned int xi2 = __float_as_uint(x2);

  float sx0 = 0.f, sy0 = 0.f, sx1 = 0.f, sy1 = 0.f, sx2 = 0.f, sy2 = 0.f;

#define FMA1(R, JJ, PAT)                                                       \
  {                                                                            \
    float xe_ = __uint_as_float(__builtin_amdgcn_ds_swizzle(xi##R, PAT));      \
    sx##R += xe_ * __uint_as_float(u##R##_##JJ << 16);                         \
    sy##R += xe_ * __uint_as_float(u##R##_##JJ & 0xffff0000u);                 \
  }
  FMA1(0, 0, 0x18) FMA1(0, 1, 0x38) FMA1(0, 2, 0x58) FMA1(0, 3, 0x78)
  FMA1(0, 4, 0x98) FMA1(0, 5, 0xb8) FMA1(0, 6, 0xd8) FMA1(0, 7, 0xf8)
  FMA1(1, 0, 0x18) FMA1(1, 1, 0x38) FMA1(1, 2, 0x58) FMA1(1, 3, 0x78)
  FMA1(1, 4, 0x98) FMA1(1, 5, 0xb8) FMA1(1, 6, 0xd8) FMA1(1, 7, 0xf8)
  FMA1(2, 0, 0x18) FMA1(2, 1, 0x38) FMA1(2, 2, 0x58) FMA1(2, 3, 0x78)
  FMA1(2, 4, 0x98) FMA1(2, 5, 0xb8) FMA1(2, 6, 0xd8) FMA1(2, 7, 0xf8)
#undef FMA1

  // tails: chunks 2+ per rel, R2-style; first col (cm) already in flight
#define TAIL(R)                                                                \
  if (st##R + 8 < ee##R) {                                                     \
    int bb = st##R + 8;                                                        \
    int cvt = cm##R;                                                           \
    float evt = elp##R[cvt * 8 + h];                                           \
    for (;;) {                                                                 \
      int ni = bb + 8 + eoff;                                                  \
      int cmt = clp##R[ni < la##R ? ni : la##R];                               \
      float e_ = evt + erv##R;                                                 \
      e_ = fmaxf(e_, 0.2f * e_);                                               \
      float x_ = (bb + eoff < ee##R) ? __expf(e_) : 0.f;                       \
      den##R += x_;                                                            \
      unsigned int xt_ = __float_as_uint(x_);                                  \
      unsigned int t0, t1, t2, t3, t4, t5, t6, t7;                             \
      {                                                                        \
        int s_;                                                                \
        s_ = __builtin_amdgcn_readlane(cvt, 0);                                \
        t0 = *(const unsigned int*)(hpb##R + (size_t)s_ * 256 + lane4);        \
        s_ = __builtin_amdgcn_readlane(cvt, 1);                                \
        t1 = *(const unsigned int*)(hpb##R + (size_t)s_ * 256 + lane4);        \
        s_ = __builtin_amdgcn_readlane(cvt, 2);                                \
        t2 = *(const unsigned int*)(hpb##R + (size_t)s_ * 256 + lane4);        \
        s_ = __builtin_amdgcn_readlane(cvt, 3);                                \
        t3 = *(const unsigned int*)(hpb##R + (size_t)s_ * 256 + lane4);        \
        s_ = __builtin_amdgcn_readlane(cvt, 4);                                \
        t4 = *(const unsigned int*)(hpb##R + (size_t)s_ * 256 + lane4);        \
        s_ = __builtin_amdgcn_readlane(cvt, 5);                                \
        t5 = *(const unsigned int*)(hpb##R + (size_t)s_ * 256 + lane4);        \
        s_ = __builtin_amdgcn_readlane(cvt, 6);                                \
        t6 = *(const unsigned int*)(hpb##R + (size_t)s_ * 256 + lane4);        \
        s_ = __builtin_amdgcn_readlane(cvt, 7);                                \
        t7 = *(const unsigned int*)(hpb##R + (size_t)s_ * 256 + lane4);        \
      }                                                                        \
      {                                                                        \
        float xe_;                                                             \
        xe_ = __uint_as_float(__builtin_amdgcn_ds_swizzle(xt_, 0x18));         \
        sx##R += xe_ * __uint_as_float(t0 << 16);                              \
        sy##R += xe_ * __uint_as_float(t0 & 0xffff0000u);                      \
        xe_ = __uint_as_float(__builtin_amdgcn_ds_swizzle(xt_, 0x38));         \
        sx##R += xe_ * __uint_as_float(t1 << 16);                              \
        sy##R += xe_ * __uint_as_float(t1 & 0xffff0000u);                      \
        xe_ = __uint_as_float(__builtin_amdgcn_ds_swizzle(xt_, 0x58));         \
        sx##R += xe_ * __uint_as_float(t2 << 16);                              \
        sy##R += xe_ * __uint_as_float(t2 & 0xffff0000u);                      \
        xe_ = __uint_as_float(__builtin_amdgcn_ds_swizzle(xt_, 0x78));         \
        sx##R += xe_ * __uint_as_float(t3 << 16);                              \
        sy##R += xe_ * __uint_as_float(t3 & 0xffff0000u);                      \
        xe_ = __uint_as_float(__builtin_amdgcn_ds_swizzle(xt_, 0x98));         \
        sx##R += xe_ * __uint_as_float(t4 << 16);                              \
        sy##R += xe_ * __uint_as_float(t4 & 0xffff0000u);                      \
        xe_ = __uint_as_float(__builtin_amdgcn_ds_swizzle(xt_, 0xb8));         \
        sx##R += xe_ * __uint_as_float(t5 << 16);                              \
        sy##R += xe_ * __uint_as_float(t5 & 0xffff0000u);                      \
        xe_ = __uint_as_float(__builtin_amdgcn_ds_swizzle(xt_, 0xd8));         \
        sx##R += xe_ * __uint_as_float(t6 << 16);                              \
        sy##R += xe_ * __uint_as_float(t6 & 0xffff0000u);                      \
        xe_ = __uint_as_float(__builtin_amdgcn_ds_swizzle(xt_, 0xf8));         \
        sx##R += xe_ * __uint_as_float(t7 << 16);                              \
        sy##R += xe_ * __uint_as_float(t7 & 0xffff0000u);                      \
      }                                                                        \
      bb += 8;                                                                 \
      if (bb >= ee##R) break;                                                  \
      evt = elp##R[cmt * 8 + h];                                               \
      cvt = cmt;                                                               \
    }                                                                          \
  }
  TAIL(0)
  TAIL(1)
  TAIL(2)
#undef TAIL

  float ax = 0.f, ay = 0.f;
  if (ee0 > st0) {
    float d = den0;
    d += __shfl_xor(d, 1); d += __shfl_xor(d, 2); d += __shfl_xor(d, 4);
    float inv = 1.f / d;
    ax += sx0 * inv; ay += sy0 * inv;
  }
  if (ee1 > st1) {
    float d = den1;
    d += __shfl_xor(d, 1); d += __shfl_xor(d, 2); d += __shfl_xor(d, 4);
    float inv = 1.f / d;
    ax += sx1 * inv; ay += sy1 * inv;
  }
  if (ee2 > st2) {
    float d = den2;
    d += __shfl_xor(d, 1); d += __shfl_xor(d, 2); d += __shfl_xor(d, 4);
    float inv = 1.f / d;
    ax += sx2 * inv; ay += sy2 * inv;
  }

  float bx = b[c] + b[128 + c] + b[256 + c];
  float by = b[c + 1] + b[128 + c + 1] + b[256 + c + 1];
  float2* hptr = (float2*)&h1[(size_t)wid * 128 + c];
  if (mode == 0) {
    *hptr = make_float2(fmaxf(ax + bx, 0.f), fmaxf(ay + by, 0.f));
  } else {
    float2 r1 = *hptr;
    float vx = ax + bx + r1.x;
    float vy = ay + by + r1.y;
    float s = vx + vy;
#pragma unroll
    for (int off = 32; off; off >>= 1) s += __shfl_xor(s, off);
    float mu = s * (1.f / 128.f);
    float dx = vx - mu, dy = vy - mu;
    float sq = dx * dx + dy * dy;
#pragma unroll
    for (int off = 32; off; off >>= 1) sq += __shfl_xor(sq, off);
    float rstd = rsqrtf(sq * (1.f / 128.f) + 1e-5f);
    *hptr = make_float2(dx * rstd * g[c] + beta[c],
                        dy * rstd * g[c + 1] + beta[c + 1]);
  }
}

extern "C" void kernel_launch(void* const* d_in, const int* in_sizes, int n_in,
                              void* d_out, int out_size, void* d_ws, size_t ws_size,
                              hipStream_t stream) {
  const float* feat = (const float*)d_in[0];
  const int* esrc = (const int*)d_in[1];
  const int* edst = (const int*)d_in[2];
  const float* W1 = (const float*)d_in[3];
  const float* al1 = (const float*)d_in[4];
  const float* ar1 = (const float*)d_in[5];
  const float* b1 = (const float*)d_in[6];
  const float* W2 = (const float*)d_in[7];
  const float* al2 = (const float*)d_in[8];
  const float* ar2 = (const float*)d_in[9];
  const float* b2 = (const float*)d_in[10];
  const float* lng = (const float*)d_in[11];
  const float* lnb = (const float*)d_in[12];
  const float* Wc1 = (const float*)d_in[13];
  const float* bc1 = (const float*)d_in[14];
  const float* Wc2 = (const float*)d_in[15];
  const float* bc2 = (const float*)d_in[16];
  float* out = (float*)d_out;

  // workspace layout
  unsigned short* hp = (unsigned short*)d_ws;            // 3*NN*128 bf16
  float* el = (float*)(hp + (size_t)3 * NN * 128);       // 3*NN*8 f32
  float* er = el + (size_t)3 * NN * 8;                   // 3*NN*8 f32
  float* h1 = er + (size_t)3 * NN * 8;                   // NN*128 f32
  int* rowptr = (int*)(h1 + (size_t)NN * 128);           // 3*(NN+1)
  int* col = rowptr + NREL * (NN + 1);                   // 3*NE
  int* cnt = col + (size_t)NREL * NE;                    // 3*NN
  int* partials = cnt + NREL * NN;                       // 3*NCH
  unsigned short* Wt = (unsigned short*)(((uintptr_t)(partials + NREL * NCH) + 15)
                                         & ~(uintptr_t)15);  // 7*144*128 bf16
  int* rank = (int*)el;  // alias: rank (3*NE) dead before first el write

  const int gemm_grid = (NN + 63) / 64;          // 782
  const int edge_grid = (NREL * NE + 255) / 256; // 4688
  const int gg_grid = (NN * 64) / 256;           // 12500 (wave per dst)

  // --- weight prep (bf16 transpose + fused wal/war columns) ---
  prep_wt<<<56, 256, 0, stream>>>(W1, W2, Wc1, Wt);
  prep_attn<<<6, 256, 0, stream>>>(W1, W2, al1, ar1, al2, ar2, Wt);

  // --- CSR build (edges shared by both layers) ---
  (void)hipMemsetAsync(cnt, 0, (size_t)NREL * NN * sizeof(int), stream);
  hist_kernel<<<edge_grid, 256, 0, stream>>>(edst, cnt, rank);
  scan1<<<NREL * NCH, 256, 0, stream>>>(cnt, partials);
  scan2<<<NREL, 256, 0, stream>>>(partials);
  scan3<<<NREL * NCH, 256, 0, stream>>>(cnt, partials, rowptr);
  scatter_kernel<<<edge_grid, 256, 0, stream>>>(esrc, edst, rowptr, rank, col);

  // --- layer 1 ---
  gemm3_attn_mfma<<<gemm_grid, 256, 0, stream>>>(feat, Wt, hp, el, er, NN);
  gather_all<<<gg_grid, 256, 0, stream>>>(rowptr, col, el, er, hp, b1,
                                          h1, nullptr, nullptr, 0);
  // --- layer 2 ---
  gemm3_attn_mfma<<<gemm_grid, 256, 0, stream>>>(
      h1, Wt + (size_t)3 * 144 * 128, hp, el, er, NN);
  gather_all<<<gg_grid, 256, 0, stream>>>(rowptr, col, el, er, hp, b2,
                                          h1, lng, lnb, 1);
  // --- classifier head ---
  gemm_head_mfma<<<gemm_grid, 256, 0, stream>>>(
      h1, Wt + (size_t)6 * 144 * 128, bc1, Wc2, bc2, out, NN);
}